// Round 13
// baseline (135.122 us; speedup 1.0000x reference)
//
#include <hip/hip_runtime.h>

// Problem constants (B=1 fixed by reference)
#define HW_TOTAL (480 * 640)           // 307200 pixels
#define NC 12                           // output channels (C-1)
#define VOX_TOTAL_C (240 * 144 * 240)   // 8,294,400 voxels (divisible by 32)

#define REC_STRIDE 16                   // floats per voxel record (64 B line)
#define NGROUPS (VOX_TOTAL_C / 4)       // 2,073,600 4-voxel groups
#define GBLOCKS (NGROUPS / 256)         // 8100 group-blocks (exact)

typedef float f32x4 __attribute__((ext_vector_type(4)));

// ---------------------------------------------------------------------------
// k1 (after 1 MB bitmap memset): scatter pixel records. REGULAR stores (R8
// lesson: NT scatter stores are 64 scattered partial-line writes per instr;
// regular stores let L2 merge the 4 16-B stores into one full dirty line).
// x reads pixel-indexed -> coalesced. bitmap bit via atomicOr (map values
// unique -> no rec conflicts; atomicOr commutative -> deterministic).
__global__ void scatter_rec_kernel(const float* __restrict__ x,
                                   const int* __restrict__ map,
                                   float* __restrict__ rec,
                                   unsigned int* __restrict__ bitmap) {
    int p = blockIdx.x * blockDim.x + threadIdx.x;
    if (p >= HW_TOTAL) return;
    int v = map[p];
    if (v <= 0) return;                 // invalid pixel (dropped)
    float vals[NC];
#pragma unroll
    for (int c = 0; c < NC; ++c)
        vals[c] = x[(size_t)(c + 1) * HW_TOTAL + p];
    f32x4* dst = (f32x4*)(rec + (size_t)v * REC_STRIDE);
    f32x4 a = {vals[0], vals[1], vals[2],  vals[3]};
    f32x4 b = {vals[4], vals[5], vals[6],  vals[7]};
    f32x4 c4 = {vals[8], vals[9], vals[10], vals[11]};
    f32x4 z = {0.f, 0.f, 0.f, 0.f};
    dst[0] = a; dst[1] = b; dst[2] = c4; dst[3] = z;   // full 64-B line
    atomicOr(&bitmap[v >> 5], 1u << (v & 31));
}

// ---------------------------------------------------------------------------
// k2: streaming gather — R9's geometry (cq-split, 4 store streams/wave, the
// best of the shaping ladder {48:147, 12:104, 4:96.2, 4x4:105, 1xburst:111,
// 1xlong:118} us) with ONE change: REGULAR stores instead of NT. This is the
// only untested {store-type x stream-count} cell, and the 6.75 TB/s fill
// kernel is regular-store. Theory: R7's regular-store regression (148 us at
// 12 streams) was L2-eviction-order scramble of the writeback stream; at 4
// streams/wave it may vanish. If this regresses, NT x 4 (R9) is the measured
// pattern ceiling -> revert + declare roofline.
__global__ void gather_rec_kernel(const float* __restrict__ rec,
                                  const unsigned int* __restrict__ bitmap,
                                  float* __restrict__ out) {
    const int b = blockIdx.x;
    const int cq = b % 3;                            // channel-quad 0..2
    const int g = (b / 3) * 256 + threadIdx.x;       // 4-voxel group (exact fit)
    unsigned int word = bitmap[g >> 3];              // 8 groups share a word
    unsigned int nib = (word >> ((g & 7) * 4)) & 0xFu;
    size_t base = (size_t)g * 4;

    f32x4 A[4];
    const f32x4 z = {0.f, 0.f, 0.f, 0.f};
    A[0] = z; A[1] = z; A[2] = z; A[3] = z;
    if (nib) {                                       // rare: gated loads only
#pragma unroll
        for (int k = 0; k < 4; ++k) {
            if (nib & (1u << k)) {
                A[k] = *(const f32x4*)(rec + (base + (size_t)k) * REC_STRIDE
                                           + (size_t)cq * 4);
            }
        }
    }
    const int c0 = cq * 4;
    // Single unconditional store path — 4 full-line regular streams per wave.
#pragma unroll
    for (int c = 0; c < 4; ++c) {
        f32x4 o = { A[0][c], A[1][c], A[2][c], A[3][c] };
        *(f32x4*)(out + (size_t)(c0 + c) * VOX_TOTAL_C + base) = o;
    }
}

// ---------------------------------------------------------------------------
// Fallback (only if ws_size were too small): memset + naive scatter (R1 path).
__global__ void naive_scatter_kernel(const float* __restrict__ x,
                                     const int* __restrict__ map,
                                     float* __restrict__ out) {
    int p = blockIdx.x * blockDim.x + threadIdx.x;
    if (p >= HW_TOTAL) return;
    int v = map[p];
    if (v <= 0) return;
#pragma unroll
    for (int c = 0; c < NC; ++c)
        out[(size_t)c * VOX_TOTAL_C + (size_t)v] = x[(size_t)(c + 1) * HW_TOTAL + p];
}

extern "C" void kernel_launch(void* const* d_in, const int* in_sizes, int n_in,
                              void* d_out, int out_size, void* d_ws, size_t ws_size,
                              hipStream_t stream) {
    const float* x = (const float*)d_in[0];      // (1, 13, 480, 640) f32
    const int* map = (const int*)d_in[1];        // (1, 307200) i32
    float* out = (float*)d_out;                  // (1, 12, 240, 144, 240) f32

    const size_t rec_bytes = (size_t)VOX_TOTAL_C * REC_STRIDE * sizeof(float); // 531 MB
    const size_t bitmap_bytes = VOX_TOTAL_C / 8;                               // 1.04 MB

    if (ws_size < rec_bytes + bitmap_bytes) {
        // Safety net (ws is ~1.59 GB in this harness; shouldn't trigger).
        hipMemsetAsync(out, 0, (size_t)NC * VOX_TOTAL_C * sizeof(float), stream);
        naive_scatter_kernel<<<HW_TOTAL / 256, 256, 0, stream>>>(x, map, out);
        return;
    }

    float* rec = (float*)d_ws;
    unsigned int* bitmap = (unsigned int*)((char*)d_ws + rec_bytes);

    // Zero only the bitmap (1 MB) every call; rec is gated by bitmap bits.
    hipMemsetAsync(bitmap, 0, bitmap_bytes, stream);

    scatter_rec_kernel<<<HW_TOTAL / 256, 256, 0, stream>>>(x, map, rec, bitmap);

    // gather: 3 channel-quads x 8100 group-blocks = 24300 blocks
    gather_rec_kernel<<<GBLOCKS * 3, 256, 0, stream>>>(rec, bitmap, out);
}

// Round 14
// 94.860 us; speedup vs baseline: 1.4244x; 1.4244x over previous
//
#include <hip/hip_runtime.h>

// Problem constants (B=1 fixed by reference)
#define HW_TOTAL (480 * 640)           // 307200 pixels
#define NC 12                           // output channels (C-1)
#define VOX_TOTAL_C (240 * 144 * 240)   // 8,294,400 voxels (divisible by 32)

#define REC_STRIDE 16                   // floats per voxel record (64 B line)
#define NGROUPS (VOX_TOTAL_C / 4)       // 2,073,600 4-voxel groups
#define GBLOCKS (NGROUPS / 256)         // 8100 group-blocks (exact)

typedef float f32x4 __attribute__((ext_vector_type(4)));

// ---------------------------------------------------------------------------
// FINAL (R9 config — measured optimum of the fully-explored design grid):
//   {store-type: NT||regular} x {streams/wave: 48,12,4,1} x {run: burst,long}
//   -> NT x 4-streams x 1-burst = 96.2 us; all other cells 104-148 us.
// Ceiling arithmetic: gather 417 MB @ ~5.4 TB/s NT-path + scatter + memset +
// launch gaps ~= 92-96 us structural floor == observed.
// ---------------------------------------------------------------------------
// k1 (after 1 MB bitmap memset): scatter pixel records. REGULAR stores (R8:
// NT scatter stores are 64 scattered partial-line writes per instr; regular
// stores let L2 merge the 4 16-B stores into one full dirty line before
// writeback). x reads pixel-indexed -> coalesced. bitmap bit via atomicOr
// (map values unique -> no rec conflicts; atomicOr commutative ->
// deterministic).
__global__ void scatter_rec_kernel(const float* __restrict__ x,
                                   const int* __restrict__ map,
                                   float* __restrict__ rec,
                                   unsigned int* __restrict__ bitmap) {
    int p = blockIdx.x * blockDim.x + threadIdx.x;
    if (p >= HW_TOTAL) return;
    int v = map[p];
    if (v <= 0) return;                 // invalid pixel (dropped)
    float vals[NC];
#pragma unroll
    for (int c = 0; c < NC; ++c)
        vals[c] = x[(size_t)(c + 1) * HW_TOTAL + p];
    f32x4* dst = (f32x4*)(rec + (size_t)v * REC_STRIDE);
    f32x4 a = {vals[0], vals[1], vals[2],  vals[3]};
    f32x4 b = {vals[4], vals[5], vals[6],  vals[7]};
    f32x4 c4 = {vals[8], vals[9], vals[10], vals[11]};
    f32x4 z = {0.f, 0.f, 0.f, 0.f};
    dst[0] = a; dst[1] = b; dst[2] = c4; dst[3] = z;   // full 64-B line
    atomicOr(&bitmap[v >> 5], 1u << (v & 31));
}

// ---------------------------------------------------------------------------
// k2: streaming gather, channel-quad split. Block b: channel-quad cq = b%3
// (channels 4cq..4cq+3), group range (b/3)*256 .. +255. Each wave writes 4
// NT store streams — the measured optimum of the stream ladder. Valid voxels
// load one 16-B f32x4 slice of their rec line; the 3 dispatch-adjacent
// cq-blocks sharing a group range hit the same rec lines via L3. Single
// unconditional NT store path (R5: divergent store paths -> partial-line NT
// writes; R7/R13: regular stores -> L2 thrash vs rec loads, 135-148 us).
__global__ void gather_rec_kernel(const float* __restrict__ rec,
                                  const unsigned int* __restrict__ bitmap,
                                  float* __restrict__ out) {
    const int b = blockIdx.x;
    const int cq = b % 3;                            // channel-quad 0..2
    const int g = (b / 3) * 256 + threadIdx.x;       // 4-voxel group (exact fit)
    unsigned int word = bitmap[g >> 3];              // 8 groups share a word
    unsigned int nib = (word >> ((g & 7) * 4)) & 0xFu;
    size_t base = (size_t)g * 4;

    f32x4 A[4];
    const f32x4 z = {0.f, 0.f, 0.f, 0.f};
    A[0] = z; A[1] = z; A[2] = z; A[3] = z;
    if (nib) {                                       // rare: gated loads only
#pragma unroll
        for (int k = 0; k < 4; ++k) {
            if (nib & (1u << k)) {
                A[k] = *(const f32x4*)(rec + (base + (size_t)k) * REC_STRIDE
                                           + (size_t)cq * 4);
            }
        }
    }
    const int c0 = cq * 4;
    // Single unconditional store path — 4 full-line NT streams per wave.
#pragma unroll
    for (int c = 0; c < 4; ++c) {
        f32x4 o = { A[0][c], A[1][c], A[2][c], A[3][c] };
        __builtin_nontemporal_store(o,
            (f32x4*)(out + (size_t)(c0 + c) * VOX_TOTAL_C + base));
    }
}

// ---------------------------------------------------------------------------
// Fallback (only if ws_size were too small): memset + naive scatter (R1 path).
__global__ void naive_scatter_kernel(const float* __restrict__ x,
                                     const int* __restrict__ map,
                                     float* __restrict__ out) {
    int p = blockIdx.x * blockDim.x + threadIdx.x;
    if (p >= HW_TOTAL) return;
    int v = map[p];
    if (v <= 0) return;
#pragma unroll
    for (int c = 0; c < NC; ++c)
        out[(size_t)c * VOX_TOTAL_C + (size_t)v] = x[(size_t)(c + 1) * HW_TOTAL + p];
}

extern "C" void kernel_launch(void* const* d_in, const int* in_sizes, int n_in,
                              void* d_out, int out_size, void* d_ws, size_t ws_size,
                              hipStream_t stream) {
    const float* x = (const float*)d_in[0];      // (1, 13, 480, 640) f32
    const int* map = (const int*)d_in[1];        // (1, 307200) i32
    float* out = (float*)d_out;                  // (1, 12, 240, 144, 240) f32

    const size_t rec_bytes = (size_t)VOX_TOTAL_C * REC_STRIDE * sizeof(float); // 531 MB
    const size_t bitmap_bytes = VOX_TOTAL_C / 8;                               // 1.04 MB

    if (ws_size < rec_bytes + bitmap_bytes) {
        // Safety net (ws is ~1.59 GB in this harness; shouldn't trigger).
        hipMemsetAsync(out, 0, (size_t)NC * VOX_TOTAL_C * sizeof(float), stream);
        naive_scatter_kernel<<<HW_TOTAL / 256, 256, 0, stream>>>(x, map, out);
        return;
    }

    float* rec = (float*)d_ws;
    unsigned int* bitmap = (unsigned int*)((char*)d_ws + rec_bytes);

    // Zero only the bitmap (1 MB) every call; rec is gated by bitmap bits.
    hipMemsetAsync(bitmap, 0, bitmap_bytes, stream);

    scatter_rec_kernel<<<HW_TOTAL / 256, 256, 0, stream>>>(x, map, rec, bitmap);

    // gather: 3 channel-quads x 8100 group-blocks = 24300 blocks
    gather_rec_kernel<<<GBLOCKS * 3, 256, 0, stream>>>(rec, bitmap, out);
}